// Round 6
// baseline (17788.695 us; speedup 1.0000x reference)
//
#include <hip/hip_runtime.h>

#define NB_ROWS 65536

static __device__ __forceinline__ ushort f2bf(float f) {
  union { float f; unsigned u; } v; v.f = f;
  unsigned r = v.u + 0x7fffu + ((v.u >> 16) & 1u);
  return (ushort)(r >> 16);
}
static __device__ __forceinline__ float bf2f(ushort h) {
  union { unsigned u; float f; } v; v.u = ((unsigned)h) << 16;
  return v.f;
}
static __device__ __forceinline__ float silu_f(float x) {
  return x / (1.0f + expf(-x));
}

// One fully-fused kernel: NO workspace. 64 rows per block, 512 threads.
// OUTPUTS ARE FLOAT32 (reference returns jnp.float32).
// LDS: xt[64][648] bf16 (~81KB) + sH[64*256] f32 (64KB) + sG (2KB) = ~148KB.
__global__ __launch_bounds__(512) void fused_all(
    const float* __restrict__ zt, const float* __restrict__ tin,
    const float* __restrict__ cond,
    const float* __restrict__ tW1, const float* __restrict__ tb1,
    const float* __restrict__ tW2, const float* __restrict__ tb2,
    const float* __restrict__ eW1, const float* __restrict__ eb1,
    const float* __restrict__ eW2, const float* __restrict__ eb2,
    const float* __restrict__ eW3, const float* __restrict__ eb3,
    const float* __restrict__ rW1, const float* __restrict__ rb1,
    const float* __restrict__ rW2, const float* __restrict__ rb2,
    float* __restrict__ velout, float* __restrict__ gateout) {
  __shared__ ushort xt[64][648];   // x tile: [z 0:256 | te 256:384 | cond 384:640]
  __shared__ float sH[64 * 256];   // emb/h_t, then rh, then expert hidden
  __shared__ float sG[64 * 8];     // gates

  const int tid = threadIdx.x;
  const int row0 = blockIdx.x * 64;

  // ---- 1) z & cond -> xt (bf16) ----
  for (int i = tid; i < 64 * 64; i += 512) {
    int r = i >> 6;
    int c4 = (i & 63) << 2;
    size_t g = (size_t)(row0 + r);
    float4 zv = *(const float4*)&zt[g * 256 + c4];
    ushort4 o; o.x = f2bf(zv.x); o.y = f2bf(zv.y); o.z = f2bf(zv.z); o.w = f2bf(zv.w);
    *(ushort4*)&xt[r][c4] = o;
    float4 cv = *(const float4*)&cond[g * 256 + c4];
    ushort4 p; p.x = f2bf(cv.x); p.y = f2bf(cv.y); p.z = f2bf(cv.z); p.w = f2bf(cv.w);
    *(ushort4*)&xt[r][384 + c4] = p;
  }
  // ---- 2) sinusoidal emb -> sH[0:8192]  ([r][j], stride 128) ----
  const float S = -9.210340371976184f / 63.0f;   // -ln(10000)/63
  for (int i = tid; i < 64 * 128; i += 512) {
    int r = i >> 7;
    int j = i & 127;
    float tv = tin[row0 + r];
    float v = (j < 64) ? sinf(tv * expf((float)j * S))
                       : cosf(tv * expf((float)(j - 64) * S));
    sH[i] = v;
  }
  __syncthreads();

  const int rr8 = tid >> 3;       // 0..63 (row), 8 col-groups of 16
  const int q8 = tid & 7;

  // ---- 3) h_t = silu(emb @ tW1 + tb1) -> sH[8192:16384] ----
  {
    float acc[16];
    #pragma unroll
    for (int c = 0; c < 16; ++c) acc[c] = 0.f;
    for (int k = 0; k < 128; ++k) {
      float ev = sH[rr8 * 128 + k];
      const float* wr = &tW1[k * 128 + q8 * 16];
      #pragma unroll
      for (int c4 = 0; c4 < 4; ++c4) {
        float4 wv = *(const float4*)&wr[c4 * 4];
        acc[c4 * 4 + 0] += ev * wv.x;
        acc[c4 * 4 + 1] += ev * wv.y;
        acc[c4 * 4 + 2] += ev * wv.z;
        acc[c4 * 4 + 3] += ev * wv.w;
      }
    }
    #pragma unroll
    for (int c = 0; c < 16; ++c) {
      int col = q8 * 16 + c;
      sH[8192 + rr8 * 128 + col] = silu_f(acc[c] + tb1[col]);  // disjoint region
    }
  }
  __syncthreads();

  // ---- 4) te = h_t @ tW2 + tb2 -> xt cols 256..383 ----
  {
    float acc[16];
    #pragma unroll
    for (int c = 0; c < 16; ++c) acc[c] = 0.f;
    for (int k = 0; k < 128; ++k) {
      float hv = sH[8192 + rr8 * 128 + k];
      const float* wr = &tW2[k * 128 + q8 * 16];
      #pragma unroll
      for (int c4 = 0; c4 < 4; ++c4) {
        float4 wv = *(const float4*)&wr[c4 * 4];
        acc[c4 * 4 + 0] += hv * wv.x;
        acc[c4 * 4 + 1] += hv * wv.y;
        acc[c4 * 4 + 2] += hv * wv.z;
        acc[c4 * 4 + 3] += hv * wv.w;
      }
    }
    #pragma unroll
    for (int c = 0; c < 16; ++c) {
      int col = q8 * 16 + c;
      xt[rr8][256 + col] = f2bf(acc[c] + tb2[col]);
    }
  }
  __syncthreads();   // te visible before router reads x

  // ---- 5) rh = silu(x @ rW1 + rb1) -> sH[0:8192] ----
  {
    float acc[16];
    #pragma unroll
    for (int c = 0; c < 16; ++c) acc[c] = 0.f;
    for (int k = 0; k < 640; ++k) {
      float xv = bf2f(xt[rr8][k]);
      const float* wr = &rW1[k * 128 + q8 * 16];
      #pragma unroll
      for (int c4 = 0; c4 < 4; ++c4) {
        float4 wv = *(const float4*)&wr[c4 * 4];
        acc[c4 * 4 + 0] += xv * wv.x;
        acc[c4 * 4 + 1] += xv * wv.y;
        acc[c4 * 4 + 2] += xv * wv.z;
        acc[c4 * 4 + 3] += xv * wv.w;
      }
    }
    __syncthreads();   // emb/h_t reads complete before overwrite
    #pragma unroll
    for (int c = 0; c < 16; ++c) {
      int col = q8 * 16 + c;
      sH[rr8 * 128 + col] = silu_f(acc[c] + rb1[col]);
    }
  }
  __syncthreads();

  // ---- 6) logits + softmax -> sG, gateout (f32) ----
  if (tid < 64) {
    float a[8];
    #pragma unroll
    for (int e = 0; e < 8; ++e) a[e] = rb2[e];
    for (int i = 0; i < 128; ++i) {
      float h = sH[tid * 128 + i];
      const float* wr = &rW2[i * 8];
      #pragma unroll
      for (int e = 0; e < 8; ++e) a[e] += h * wr[e];
    }
    float mx = a[0];
    #pragma unroll
    for (int e = 1; e < 8; ++e) mx = fmaxf(mx, a[e]);
    float s = 0.f, ex[8];
    #pragma unroll
    for (int e = 0; e < 8; ++e) { ex[e] = expf(a[e] - mx); s += ex[e]; }
    float inv = 1.f / s;
    #pragma unroll
    for (int e = 0; e < 8; ++e) {
      float g = ex[e] * inv;
      sG[tid * 8 + e] = g;
      gateout[(size_t)(row0 + tid) * 8 + e] = g;   // FLOAT32 output
    }
  }
  __syncthreads();   // sG visible; all sH (rh) reads complete

  // ---- 7) expert loop ----
  const int rg = tid >> 4;        // 0..31 -> rows rg*2, rg*2+1
  const int tq = tid & 15;        // cols tq*16 .. +15
  float va[2][16];
  #pragma unroll
  for (int i = 0; i < 2; ++i)
    #pragma unroll
    for (int c = 0; c < 16; ++c) va[i][c] = 0.f;

  for (int e = 0; e < 8; ++e) {
    const float* W1 = eW1 + (size_t)e * 640 * 256;
    const float* W2 = eW2 + (size_t)e * 256 * 256;
    const float* W3 = eW3 + (size_t)e * 256 * 256;

    // h1 = silu(x @ W1 + eb1[e])   (reads xt only)
    float a1[2][16];
    #pragma unroll
    for (int i = 0; i < 2; ++i)
      #pragma unroll
      for (int c = 0; c < 16; ++c) a1[i][c] = 0.f;
    for (int k = 0; k < 640; ++k) {
      float x0 = bf2f(xt[rg * 2 + 0][k]);
      float x1 = bf2f(xt[rg * 2 + 1][k]);
      const float* wr = &W1[(size_t)k * 256 + tq * 16];
      #pragma unroll
      for (int c4 = 0; c4 < 4; ++c4) {
        float4 wv = *(const float4*)&wr[c4 * 4];
        a1[0][c4 * 4 + 0] += x0 * wv.x; a1[1][c4 * 4 + 0] += x1 * wv.x;
        a1[0][c4 * 4 + 1] += x0 * wv.y; a1[1][c4 * 4 + 1] += x1 * wv.y;
        a1[0][c4 * 4 + 2] += x0 * wv.z; a1[1][c4 * 4 + 2] += x1 * wv.z;
        a1[0][c4 * 4 + 3] += x0 * wv.w; a1[1][c4 * 4 + 3] += x1 * wv.w;
      }
    }
    __syncthreads();   // prior readers of sH done (logits / prev expert W3)
    #pragma unroll
    for (int i = 0; i < 2; ++i)
      #pragma unroll
      for (int c = 0; c < 16; ++c) {
        int col = tq * 16 + c;
        sH[(rg * 2 + i) * 256 + col] = silu_f(a1[i][c] + eb1[e * 256 + col]);
      }
    __syncthreads();

    // h2 = silu(h1 @ W2 + eb2[e]), gated -> sH
    float a2[2][16];
    #pragma unroll
    for (int i = 0; i < 2; ++i)
      #pragma unroll
      for (int c = 0; c < 16; ++c) a2[i][c] = 0.f;
    for (int k = 0; k < 256; ++k) {
      float h0 = sH[(rg * 2 + 0) * 256 + k];
      float h1v = sH[(rg * 2 + 1) * 256 + k];
      const float* wr = &W2[(size_t)k * 256 + tq * 16];
      #pragma unroll
      for (int c4 = 0; c4 < 4; ++c4) {
        float4 wv = *(const float4*)&wr[c4 * 4];
        a2[0][c4 * 4 + 0] += h0 * wv.x; a2[1][c4 * 4 + 0] += h1v * wv.x;
        a2[0][c4 * 4 + 1] += h0 * wv.y; a2[1][c4 * 4 + 1] += h1v * wv.y;
        a2[0][c4 * 4 + 2] += h0 * wv.z; a2[1][c4 * 4 + 2] += h1v * wv.z;
        a2[0][c4 * 4 + 3] += h0 * wv.w; a2[1][c4 * 4 + 3] += h1v * wv.w;
      }
    }
    __syncthreads();   // all h1 reads done before overwrite
    #pragma unroll
    for (int i = 0; i < 2; ++i) {
      float gv = sG[(rg * 2 + i) * 8 + e];
      #pragma unroll
      for (int c = 0; c < 16; ++c) {
        int col = tq * 16 + c;
        sH[(rg * 2 + i) * 256 + col] = gv * silu_f(a2[i][c] + eb2[e * 256 + col]);
      }
    }
    __syncthreads();

    // velocity += (g*h2) @ W3
    for (int k = 0; k < 256; ++k) {
      float h0 = sH[(rg * 2 + 0) * 256 + k];
      float h1v = sH[(rg * 2 + 1) * 256 + k];
      const float* wr = &W3[(size_t)k * 256 + tq * 16];
      #pragma unroll
      for (int c4 = 0; c4 < 4; ++c4) {
        float4 wv = *(const float4*)&wr[c4 * 4];
        va[0][c4 * 4 + 0] += h0 * wv.x; va[1][c4 * 4 + 0] += h1v * wv.x;
        va[0][c4 * 4 + 1] += h0 * wv.y; va[1][c4 * 4 + 1] += h1v * wv.y;
        va[0][c4 * 4 + 2] += h0 * wv.z; va[1][c4 * 4 + 2] += h1v * wv.z;
        va[0][c4 * 4 + 3] += h0 * wv.w; va[1][c4 * 4 + 3] += h1v * wv.w;
      }
    }
    // next iteration's first sH write is barrier-guarded above
  }

  // ---- 8) write velocity as FLOAT32 (+ gate-weighted eb3, zeros but honored) ----
  #pragma unroll
  for (int i = 0; i < 2; ++i) {
    size_t row = (size_t)(row0 + rg * 2 + i);
    #pragma unroll
    for (int c = 0; c < 16; ++c) {
      int col = tq * 16 + c;
      float bs = 0.f;
      #pragma unroll
      for (int e = 0; e < 8; ++e) bs += sG[(rg * 2 + i) * 8 + e] * eb3[e * 256 + col];
      velout[row * 256 + col] = va[i][c] + bs;
    }
  }
}

extern "C" void kernel_launch(void* const* d_in, const int* in_sizes, int n_in,
                              void* d_out, int out_size, void* d_ws, size_t ws_size,
                              hipStream_t stream) {
  const float* zt   = (const float*)d_in[0];
  const float* tin  = (const float*)d_in[1];
  const float* cond = (const float*)d_in[2];
  const float* tW1  = (const float*)d_in[3];
  const float* tb1  = (const float*)d_in[4];
  const float* tW2  = (const float*)d_in[5];
  const float* tb2  = (const float*)d_in[6];
  const float* eW1  = (const float*)d_in[7];
  const float* eb1  = (const float*)d_in[8];
  const float* eW2  = (const float*)d_in[9];
  const float* eb2  = (const float*)d_in[10];
  const float* eW3  = (const float*)d_in[11];
  const float* eb3  = (const float*)d_in[12];
  const float* rW1  = (const float*)d_in[13];
  const float* rb1  = (const float*)d_in[14];
  const float* rW2  = (const float*)d_in[15];
  const float* rb2  = (const float*)d_in[16];

  // Reference output dtype is float32 -> d_out is float*.
  float* velout  = (float*)d_out;
  float* gateout = velout + (size_t)NB_ROWS * 256;

  fused_all<<<NB_ROWS / 64, 512, 0, stream>>>(
      zt, tin, cond, tW1, tb1, tW2, tb2,
      eW1, eb1, eW2, eb2, eW3, eb3,
      rW1, rb1, rW2, rb2, velout, gateout);
}

// Round 8
// 694.171 us; speedup vs baseline: 25.6258x; 25.6258x over previous
//
#include <hip/hip_runtime.h>

typedef __attribute__((ext_vector_type(8))) short bf16x8;
typedef __attribute__((ext_vector_type(4))) float f32x4;

#define NB_ROWS 65536
#define D_EMBED 256
#define D_HID   256
#define N_EXP   8
#define D_RHID  128
#define D_IN    640

// LDS strides (elements): K-tiles 64 -> 72 (144B rows, 16B aligned, 8-bank spread)
// h-tile 256 -> 264 (528B rows, 16B aligned)
#define KSTR 72
#define HSTR 264

static __device__ __forceinline__ ushort f2bf(float f) {
  union { float f; unsigned u; } v; v.f = f;
  unsigned r = v.u + 0x7fffu + ((v.u >> 16) & 1u);
  return (ushort)(r >> 16);
}
static __device__ __forceinline__ float bf2f(ushort h) {
  union { unsigned u; float f; } v; v.u = ((unsigned)h) << 16;
  return v.f;
}
static __device__ __forceinline__ float silu_f(float x) {
  return x / (1.0f + __expf(-x));
}

// ---------------- weight prep: [nm][R][C] f32 -> [nm][C][R] bf16 ----------------
__global__ void prep_transpose(const float* __restrict__ src, ushort* __restrict__ dst,
                               int R, int C, int total) {
  int idx = blockIdx.x * 256 + threadIdx.x;
  if (idx >= total) return;
  int rc = R * C;
  int m = idx / rc;
  int rem = idx - m * rc;
  int r = rem / C;
  int c = rem - r * C;
  dst[m * rc + c * R + r] = f2bf(src[idx]);
}

// stage a [128 rows][64 cols] bf16 K-tile (row-major global, ld elems) into LDS stride KSTR
// NT=512 threads version
static __device__ __forceinline__ void stageA128_512(const ushort* __restrict__ src, int ld,
                                                     int kt, ushort* dst, int tid) {
  uint4 v[2];
  #pragma unroll
  for (int c = 0; c < 2; ++c) {
    int f = c * 8192 + tid * 16;
    int r = f >> 7, ce = (f & 127) >> 1;
    v[c] = *(const uint4*)&src[(size_t)r * ld + kt + ce];
  }
  #pragma unroll
  for (int c = 0; c < 2; ++c) {
    int f = c * 8192 + tid * 16;
    int r = f >> 7, ce = (f & 127) >> 1;
    *(uint4*)&dst[r * KSTR + ce] = v[c];
  }
}
// stage a [256 rows][64 cols] bf16 K-tile, NT=512
static __device__ __forceinline__ void stageB256_512(const ushort* __restrict__ src, int ld,
                                                     int kt, ushort* dst, int tid) {
  uint4 v[4];
  #pragma unroll
  for (int c = 0; c < 4; ++c) {
    int f = c * 8192 + tid * 16;
    int r = f >> 7, ce = (f & 127) >> 1;
    v[c] = *(const uint4*)&src[(size_t)r * ld + kt + ce];
  }
  #pragma unroll
  for (int c = 0; c < 4; ++c) {
    int f = c * 8192 + tid * 16;
    int r = f >> 7, ce = (f & 127) >> 1;
    *(uint4*)&dst[r * KSTR + ce] = v[c];
  }
}
// stage a [128 rows][64 cols] bf16 K-tile, NT=256
static __device__ __forceinline__ void stageA128_256(const ushort* __restrict__ src, int ld,
                                                     int kt, ushort* dst, int tid) {
  uint4 v[4];
  #pragma unroll
  for (int c = 0; c < 4; ++c) {
    int f = c * 4096 + tid * 16;
    int r = f >> 7, ce = (f & 127) >> 1;
    v[c] = *(const uint4*)&src[(size_t)r * ld + kt + ce];
  }
  #pragma unroll
  for (int c = 0; c < 4; ++c) {
    int f = c * 4096 + tid * 16;
    int r = f >> 7, ce = (f & 127) >> 1;
    *(uint4*)&dst[r * KSTR + ce] = v[c];
  }
}

// ---------------- time embedding MLP + build x = [z | te | cond] (bf16) ----------------
__global__ __launch_bounds__(512) void time_x_kernel(
    const float* __restrict__ zt, const float* __restrict__ tin,
    const float* __restrict__ cond,
    const ushort* __restrict__ tw1t, const ushort* __restrict__ tw2t,
    const float* __restrict__ tb1, const float* __restrict__ tb2,
    ushort* __restrict__ x) {
  __shared__ __align__(16) ushort sE[128 * 136];
  __shared__ float sFreq[64];
  __shared__ float sB1[128];
  __shared__ float sB2[128];

  const int tid = threadIdx.x;
  const int row0 = blockIdx.x * 128;

  // copy z_t and cond slices into x
  for (int ch = tid; ch < 128 * 64; ch += 512) {
    int r = ch >> 6;
    int c4 = (ch & 63) << 2;
    size_t grow = (size_t)(row0 + r);
    float4 zv = *(const float4*)&zt[grow * 256 + c4];
    ushort4 o; o.x = f2bf(zv.x); o.y = f2bf(zv.y); o.z = f2bf(zv.z); o.w = f2bf(zv.w);
    *(ushort4*)&x[grow * 640 + c4] = o;
    float4 cv = *(const float4*)&cond[grow * 256 + c4];
    ushort4 o2; o2.x = f2bf(cv.x); o2.y = f2bf(cv.y); o2.z = f2bf(cv.z); o2.w = f2bf(cv.w);
    *(ushort4*)&x[grow * 640 + 384 + c4] = o2;
  }

  if (tid < 64) sFreq[tid] = __expf((float)tid * (-9.210340371976184f / 63.0f));
  if (tid < 128) { sB1[tid] = tb1[tid]; sB2[tid] = tb2[tid]; }
  __syncthreads();

  // sinusoidal embedding: emb = [sin(t*f) | cos(t*f)]
  {
    int r = tid >> 2;
    int qd = tid & 3;
    float tv = tin[row0 + r];
    int half = qd >> 1;
    int cbase = (qd & 1) * 32;
    ushort* er = &sE[r * 136 + half * 64 + cbase];
    #pragma unroll
    for (int c = 0; c < 32; ++c) {
      float a = tv * sFreq[cbase + c];
      float v = half ? __cosf(a) : __sinf(a);
      er[c] = f2bf(v);
    }
  }
  __syncthreads();

  const int l = tid & 63;
  const int w = tid >> 6;   // 8 waves: 4(M) x 2(N) grid of 32x64 tiles
  const int wm = w >> 1;
  const int wn = w & 1;
  const int lr = l & 15;
  const int lk = (l >> 4) * 8;
  const int q4 = (l >> 4) * 4;

  // GEMM1: h = silu(emb @ tW1 + b1)   (B fragments from global; 32KB matrix, L2-hot)
  f32x4 acc[2][4] = {};
  #pragma unroll
  for (int kk = 0; kk < 4; ++kk) {
    int kb = kk * 32 + lk;
    bf16x8 av[2], bv[4];
    #pragma unroll
    for (int mf = 0; mf < 2; ++mf)
      av[mf] = *(const bf16x8*)&sE[(wm * 32 + mf * 16 + lr) * 136 + kb];
    #pragma unroll
    for (int nf = 0; nf < 4; ++nf)
      bv[nf] = *(const bf16x8*)&tw1t[(size_t)(wn * 64 + nf * 16 + lr) * 128 + kb];
    #pragma unroll
    for (int mf = 0; mf < 2; ++mf)
      #pragma unroll
      for (int nf = 0; nf < 4; ++nf)
        acc[mf][nf] = __builtin_amdgcn_mfma_f32_16x16x32_bf16(av[mf], bv[nf], acc[mf][nf], 0, 0, 0);
  }
  __syncthreads();  // all waves done reading emb before overwrite
  #pragma unroll
  for (int mf = 0; mf < 2; ++mf)
    #pragma unroll
    for (int nf = 0; nf < 4; ++nf) {
      int cc = wn * 64 + nf * 16 + lr;
      #pragma unroll
      for (int rg = 0; rg < 4; ++rg) {
        int rr = wm * 32 + mf * 16 + q4 + rg;
        sE[rr * 136 + cc] = f2bf(silu_f(acc[mf][nf][rg] + sB1[cc]));
      }
    }
  __syncthreads();

  // GEMM2: te = h @ tW2 + b2 -> x[:, 256..383]
  f32x4 acc2[2][4] = {};
  #pragma unroll
  for (int kk = 0; kk < 4; ++kk) {
    int kb = kk * 32 + lk;
    bf16x8 av[2], bv[4];
    #pragma unroll
    for (int mf = 0; mf < 2; ++mf)
      av[mf] = *(const bf16x8*)&sE[(wm * 32 + mf * 16 + lr) * 136 + kb];
    #pragma unroll
    for (int nf = 0; nf < 4; ++nf)
      bv[nf] = *(const bf16x8*)&tw2t[(size_t)(wn * 64 + nf * 16 + lr) * 128 + kb];
    #pragma unroll
    for (int mf = 0; mf < 2; ++mf)
      #pragma unroll
      for (int nf = 0; nf < 4; ++nf)
        acc2[mf][nf] = __builtin_amdgcn_mfma_f32_16x16x32_bf16(av[mf], bv[nf], acc2[mf][nf], 0, 0, 0);
  }
  #pragma unroll
  for (int mf = 0; mf < 2; ++mf)
    #pragma unroll
    for (int nf = 0; nf < 4; ++nf) {
      int cc = wn * 64 + nf * 16 + lr;
      #pragma unroll
      for (int rg = 0; rg < 4; ++rg) {
        int rr = wm * 32 + mf * 16 + q4 + rg;
        x[(size_t)(row0 + rr) * 640 + 256 + cc] = f2bf(acc2[mf][nf][rg] + sB2[cc]);
      }
    }
}

// ---------------- fused router: rh = silu(x@rW1+b1); gate = softmax(rh@rW2+b2) ----------------
__global__ __launch_bounds__(256) void router_kernel(
    const ushort* __restrict__ xb, const ushort* __restrict__ rw1t,
    const float* __restrict__ rb1, const float* __restrict__ rW2,
    const float* __restrict__ rb2, float* __restrict__ gatef,
    float* __restrict__ gateo) {
  __shared__ __align__(16) ushort smA[128 * KSTR];
  __shared__ __align__(16) ushort smB[128 * KSTR];
  __shared__ __align__(16) ushort rhbuf[128 * 136];
  __shared__ float sW2[128 * 8];

  const int tid = threadIdx.x;
  const int row0 = blockIdx.x * 128;
  for (int i = tid; i < 1024; i += 256) sW2[i] = rW2[i];

  const int l = tid & 63;
  const int w = tid >> 6;     // 4 waves: 2x2 of 64x64
  const int wm = w >> 1, wn = w & 1;
  const int lr = l & 15, lk = (l >> 4) * 8, q4 = (l >> 4) * 4;
  const ushort* xrow = xb + (size_t)row0 * 640;

  f32x4 acc[4][4] = {};
  for (int kt = 0; kt < 640; kt += 64) {
    stageA128_256(xrow, 640, kt, smA, tid);
    stageA128_256(rw1t, 640, kt, smB, tid);
    __syncthreads();
    #pragma unroll
    for (int kk = 0; kk < 2; ++kk) {
      int kb = kk * 32 + lk;
      bf16x8 av[4], bv[4];
      #pragma unroll
      for (int mf = 0; mf < 4; ++mf)
        av[mf] = *(const bf16x8*)&smA[(wm * 64 + mf * 16 + lr) * KSTR + kb];
      #pragma unroll
      for (int nf = 0; nf < 4; ++nf)
        bv[nf] = *(const bf16x8*)&smB[(wn * 64 + nf * 16 + lr) * KSTR + kb];
      #pragma unroll
      for (int mf = 0; mf < 4; ++mf)
        #pragma unroll
        for (int nf = 0; nf < 4; ++nf)
          acc[mf][nf] = __builtin_amdgcn_mfma_f32_16x16x32_bf16(av[mf], bv[nf], acc[mf][nf], 0, 0, 0);
    }
    __syncthreads();
  }
  // epilogue: silu + bias -> rhbuf (padded stride 136)
  #pragma unroll
  for (int nf = 0; nf < 4; ++nf) {
    int cc = wn * 64 + nf * 16 + lr;
    float b1v = rb1[cc];
    #pragma unroll
    for (int mf = 0; mf < 4; ++mf)
      #pragma unroll
      for (int rg = 0; rg < 4; ++rg) {
        int rr = wm * 64 + mf * 16 + q4 + rg;
        rhbuf[rr * 136 + cc] = f2bf(silu_f(acc[mf][nf][rg] + b1v));
      }
  }
  __syncthreads();

  // logits + softmax: one thread per row
  if (tid < 128) {
    float a[8];
    #pragma unroll
    for (int e = 0; e < 8; ++e) a[e] = rb2[e];
    #pragma unroll
    for (int i8 = 0; i8 < 16; ++i8) {
      bf16x8 hv = *(const bf16x8*)&rhbuf[tid * 136 + i8 * 8];
      #pragma unroll
      for (int j = 0; j < 8; ++j) {
        float h = bf2f((ushort)hv[j]);
        const float* wrow = &sW2[(i8 * 8 + j) * 8];
        #pragma unroll
        for (int e = 0; e < 8; ++e) a[e] += h * wrow[e];
      }
    }
    float mx = a[0];
    #pragma unroll
    for (int e = 1; e < 8; ++e) mx = fmaxf(mx, a[e]);
    float s = 0.f, ex[8];
    #pragma unroll
    for (int e = 0; e < 8; ++e) { ex[e] = __expf(a[e] - mx); s += ex[e]; }
    float inv = 1.f / s;
    size_t b = (size_t)(row0 + tid);
    #pragma unroll
    for (int e = 0; e < 8; ++e) {
      float g = ex[e] * inv;
      gatef[b * 8 + e] = g;
      gateo[b * 8 + e] = g;     // FLOAT32 output
    }
  }
}

// ---------------- fused MoE: per 128-row stripe, loop experts, all in LDS/regs ----------------
__global__ __launch_bounds__(512) void moe_fused_kernel(
    const ushort* __restrict__ xb, const ushort* __restrict__ w1t,
    const ushort* __restrict__ w2t, const ushort* __restrict__ w3t,
    const float* __restrict__ eb1, const float* __restrict__ eb2,
    const float* __restrict__ eb3, const float* __restrict__ gatef,
    float* __restrict__ velout) {
  __shared__ __align__(16) ushort smA[128 * KSTR];    // 18 KB: x K-tile
  __shared__ __align__(16) ushort smB[256 * KSTR];    // 36 KB: weight K-tile (N=256)
  __shared__ __align__(16) ushort hbuf[128 * HSTR];   // 66 KB: h tile (padded)
  __shared__ float sGate[128 * 8];
  __shared__ float sEb3[8 * 256];

  const int tid = threadIdx.x;
  const int row0 = blockIdx.x * 128;
  const int l = tid & 63;
  const int w = tid >> 6;     // 8 waves: 2(M) x 4(N), wave tile 64x64
  const int wm = w >> 2;
  const int wn = w & 3;
  const int lr = l & 15;
  const int lk = (l >> 4) * 8;
  const int q4 = (l >> 4) * 4;

  for (int i = tid; i < 1024; i += 512) sGate[i] = gatef[(size_t)row0 * 8 + i];
  for (int i = tid; i < 2048; i += 512) sEb3[i] = eb3[i];

  const ushort* xrow = xb + (size_t)row0 * 640;
  f32x4 vacc[4][4] = {};
  __syncthreads();

  for (int e = 0; e < 8; ++e) {
    const ushort* W1 = w1t + (size_t)e * (256 * 640);
    const ushort* W2 = w2t + (size_t)e * (256 * 256);
    const ushort* W3 = w3t + (size_t)e * (256 * 256);

    // ---- stage 1: h1 = silu(x @ W1 + b1), K=640 ----
    f32x4 acc[4][4] = {};
    for (int kt = 0; kt < 640; kt += 64) {
      stageA128_512(xrow, 640, kt, smA, tid);
      stageB256_512(W1, 640, kt, smB, tid);
      __syncthreads();
      #pragma unroll
      for (int kk = 0; kk < 2; ++kk) {
        int kb = kk * 32 + lk;
        bf16x8 av[4], bv[4];
        #pragma unroll
        for (int mf = 0; mf < 4; ++mf)
          av[mf] = *(const bf16x8*)&smA[(wm * 64 + mf * 16 + lr) * KSTR + kb];
        #pragma unroll
        for (int nf = 0; nf < 4; ++nf)
          bv[nf] = *(const bf16x8*)&smB[(wn * 64 + nf * 16 + lr) * KSTR + kb];
        #pragma unroll
        for (int mf = 0; mf < 4; ++mf)
          #pragma unroll
          for (int nf = 0; nf < 4; ++nf)
            acc[mf][nf] = __builtin_amdgcn_mfma_f32_16x16x32_bf16(av[mf], bv[nf], acc[mf][nf], 0, 0, 0);
      }
      __syncthreads();
    }
    // epilogue 1 -> hbuf
    #pragma unroll
    for (int nf = 0; nf < 4; ++nf) {
      int cc = wn * 64 + nf * 16 + lr;
      float b1v = eb1[e * 256 + cc];
      #pragma unroll
      for (int mf = 0; mf < 4; ++mf)
        #pragma unroll
        for (int rg = 0; rg < 4; ++rg) {
          int rr = wm * 64 + mf * 16 + q4 + rg;
          hbuf[rr * HSTR + cc] = f2bf(silu_f(acc[mf][nf][rg] + b1v));
        }
    }
    __syncthreads();

    // ---- stage 2: h2g = gate * silu(h1 @ W2 + b2), K=256 ----
    #pragma unroll
    for (int mf = 0; mf < 4; ++mf)
      #pragma unroll
      for (int nf = 0; nf < 4; ++nf)
        acc[mf][nf] = (f32x4){0.f, 0.f, 0.f, 0.f};
    for (int kt = 0; kt < 256; kt += 64) {
      stageB256_512(W2, 256, kt, smB, tid);
      __syncthreads();
      #pragma unroll
      for (int kk = 0; kk < 2; ++kk) {
        int kbl = kk * 32 + lk;
        int kbh = kt + kbl;
        bf16x8 av[4], bv[4];
        #pragma unroll
        for (int mf = 0; mf < 4; ++mf)
          av[mf] = *(const bf16x8*)&hbuf[(wm * 64 + mf * 16 + lr) * HSTR + kbh];
        #pragma unroll
        for (int nf = 0; nf < 4; ++nf)
          bv[nf] = *(const bf16x8*)&smB[(wn * 64 + nf * 16 + lr) * KSTR + kbl];
        #pragma unroll
        for (int mf = 0; mf < 4; ++mf)
          #pragma unroll
          for (int nf = 0; nf < 4; ++nf)
            acc[mf][nf] = __builtin_amdgcn_mfma_f32_16x16x32_bf16(av[mf], bv[nf], acc[mf][nf], 0, 0, 0);
      }
      __syncthreads();
    }
    // epilogue 2 -> hbuf (gate folded in; all reads drained by last barrier)
    #pragma unroll
    for (int nf = 0; nf < 4; ++nf) {
      int cc = wn * 64 + nf * 16 + lr;
      float b2v = eb2[e * 256 + cc];
      #pragma unroll
      for (int mf = 0; mf < 4; ++mf)
        #pragma unroll
        for (int rg = 0; rg < 4; ++rg) {
          int rr = wm * 64 + mf * 16 + q4 + rg;
          float gv = sGate[rr * 8 + e];
          hbuf[rr * HSTR + cc] = f2bf(silu_f(acc[mf][nf][rg] + b2v) * gv);
        }
    }
    __syncthreads();

    // ---- stage 3: vacc += h2g @ W3, K=256 ----
    for (int kt = 0; kt < 256; kt += 64) {
      stageB256_512(W3, 256, kt, smB, tid);
      __syncthreads();
      #pragma unroll
      for (int kk = 0; kk < 2; ++kk) {
        int kbl = kk * 32 + lk;
        int kbh = kt + kbl;
        bf16x8 av[4], bv[4];
        #pragma unroll
        for (int mf = 0; mf < 4; ++mf)
          av[mf] = *(const bf16x8*)&hbuf[(wm * 64 + mf * 16 + lr) * HSTR + kbh];
        #pragma unroll
        for (int nf = 0; nf < 4; ++nf)
          bv[nf] = *(const bf16x8*)&smB[(wn * 64 + nf * 16 + lr) * KSTR + kbl];
        #pragma unroll
        for (int mf = 0; mf < 4; ++mf)
          #pragma unroll
          for (int nf = 0; nf < 4; ++nf)
            vacc[mf][nf] = __builtin_amdgcn_mfma_f32_16x16x32_bf16(av[mf], bv[nf], vacc[mf][nf], 0, 0, 0);
      }
      __syncthreads();
    }
  }

  // final epilogue: velocity = vacc + sum_e gate_e * eb3_e  (FLOAT32 out)
  #pragma unroll
  for (int mf = 0; mf < 4; ++mf)
    #pragma unroll
    for (int rg = 0; rg < 4; ++rg) {
      int rr = wm * 64 + mf * 16 + q4 + rg;
      const float* gp = &sGate[rr * 8];
      #pragma unroll
      for (int nf = 0; nf < 4; ++nf) {
        int cc = wn * 64 + nf * 16 + lr;
        float bsum = 0.f;
        #pragma unroll
        for (int ee = 0; ee < 8; ++ee) bsum += gp[ee] * sEb3[ee * 256 + cc];
        velout[(size_t)(row0 + rr) * D_EMBED + cc] = vacc[mf][nf][rg] + bsum;
      }
    }
}

extern "C" void kernel_launch(void* const* d_in, const int* in_sizes, int n_in,
                              void* d_out, int out_size, void* d_ws, size_t ws_size,
                              hipStream_t stream) {
  const float* zt   = (const float*)d_in[0];
  const float* tin  = (const float*)d_in[1];
  const float* cond = (const float*)d_in[2];
  const float* tW1  = (const float*)d_in[3];
  const float* tb1  = (const float*)d_in[4];
  const float* tW2  = (const float*)d_in[5];
  const float* tb2  = (const float*)d_in[6];
  const float* eW1  = (const float*)d_in[7];
  const float* eb1  = (const float*)d_in[8];
  const float* eW2  = (const float*)d_in[9];
  const float* eb2  = (const float*)d_in[10];
  const float* eW3  = (const float*)d_in[11];
  const float* eb3  = (const float*)d_in[12];
  const float* rW1  = (const float*)d_in[13];
  const float* rb1  = (const float*)d_in[14];
  const float* rW2  = (const float*)d_in[15];
  const float* rb2  = (const float*)d_in[16];

  char* wp = (char*)d_ws;
  ushort* xb    = (ushort*)wp; wp += (size_t)NB_ROWS * D_IN * 2;        // 80 MiB
  float*  gatef = (float*)wp;  wp += (size_t)NB_ROWS * 8 * 4;           // 2 MiB
  ushort* w1t   = (ushort*)wp; wp += (size_t)N_EXP * D_HID * D_IN * 2;
  ushort* w2t   = (ushort*)wp; wp += (size_t)N_EXP * D_HID * D_HID * 2;
  ushort* w3t   = (ushort*)wp; wp += (size_t)N_EXP * D_HID * D_EMBED * 2;
  ushort* rw1t  = (ushort*)wp; wp += (size_t)D_RHID * D_IN * 2;
  ushort* tw1t  = (ushort*)wp; wp += (size_t)128 * 128 * 2;
  ushort* tw2t  = (ushort*)wp; wp += (size_t)128 * 128 * 2;
  // total ~87 MiB (runs fine, rounds 2-4/7)

  // FLOAT32 outputs (reference returns jnp.float32)
  float* velout  = (float*)d_out;
  float* gateout = velout + (size_t)NB_ROWS * D_EMBED;

  // weight prep
  {
    int tot;
    tot = 128 * 128;
    prep_transpose<<<(tot + 255) / 256, 256, 0, stream>>>(tW1, tw1t, 128, 128, tot);
    prep_transpose<<<(tot + 255) / 256, 256, 0, stream>>>(tW2, tw2t, 128, 128, tot);
    tot = D_IN * D_RHID;
    prep_transpose<<<(tot + 255) / 256, 256, 0, stream>>>(rW1, rw1t, D_IN, D_RHID, tot);
    tot = N_EXP * D_IN * D_HID;
    prep_transpose<<<(tot + 255) / 256, 256, 0, stream>>>(eW1, w1t, D_IN, D_HID, tot);
    tot = N_EXP * D_HID * D_HID;
    prep_transpose<<<(tot + 255) / 256, 256, 0, stream>>>(eW2, w2t, D_HID, D_HID, tot);
    tot = N_EXP * D_HID * D_EMBED;
    prep_transpose<<<(tot + 255) / 256, 256, 0, stream>>>(eW3, w3t, D_HID, D_EMBED, tot);
  }

  time_x_kernel<<<512, 512, 0, stream>>>(zt, tin, cond, tw1t, tw2t, tb1, tb2, xb);
  router_kernel<<<512, 256, 0, stream>>>(xb, rw1t, rb1, rW2, rb2, gatef, gateout);
  moe_fused_kernel<<<512, 512, 0, stream>>>(xb, w1t, w2t, w3t, eb1, eb2, eb3, gatef, velout);
}